// Round 3
// baseline (156.936 us; speedup 1.0000x reference)
//
#include <hip/hip_runtime.h>
#include <hip/hip_bf16.h>
#include <math.h>

#define B_  8
#define S_  512
#define D_  512
#define H_  8
#define DK_ 64
#define KL_ 1024

typedef __attribute__((ext_vector_type(8))) short bf16x8;
typedef __attribute__((ext_vector_type(4))) float f32x4;

// native RNE cast: backend pairs adjacent converts into v_cvt_pk_bf16_f32
__device__ __forceinline__ unsigned short f2bf(float f) {
    __hip_bfloat16 h = __float2bfloat16(f);
    unsigned short u;
    __builtin_memcpy(&u, &h, 2);
    return u;
}
// async global->LDS, 16 B per lane; LDS dest = wave-uniform base + lane*16
__device__ __forceinline__ void gld16(const void* g, void* l) {
    __builtin_amdgcn_global_load_lds(
        (const __attribute__((address_space(1))) unsigned int*)g,
        (__attribute__((address_space(3))) unsigned int*)l, 16, 0, 0);
}

// ---------------------------------------------------------------------------
// prev cache copy + pack (blockIdx.z==0 of qkv, dispatched first: pure-BW
// traffic overlaps the compute z-slices). Also converts Wo -> bf16 for the
// out-GEMM (which launches two kernels later -> no race).
// ---------------------------------------------------------------------------
__device__ __forceinline__
void prev_copy_body(const float* __restrict__ pk, const float* __restrict__ pv,
                    float* __restrict__ kout, float* __restrict__ vout,
                    unsigned short* __restrict__ Kp, unsigned short* __restrict__ Vp,
                    unsigned char* __restrict__ smem, int pb) {
    float (*Kl)[68] = (float (*)[68])smem;             // 64*68*4 = 17408 B
    float (*Vl)[68] = (float (*)[68])(smem + 17408);   // 17408 B
    const int t = threadIdx.x;
    const int kt = pb & 7, bh = pb >> 3;
    const float* Kg = pk + (bh * KL_ + 512 + kt * 64) * DK_;
    const float* Vg = pv + (bh * KL_ + 512 + kt * 64) * DK_;
    float* Ko = kout + (bh * KL_ + kt * 64) * DK_;
    float* Vo = vout + (bh * KL_ + kt * 64) * DK_;
    #pragma unroll
    for (int it = 0; it < 4; ++it) {
        int idx = t + it * 256;                 // 1024 float4 slots
        int row = idx >> 4, c4 = idx & 15;
        float4 kv = *(const float4*)&Kg[row * 64 + c4 * 4];
        float4 vv = *(const float4*)&Vg[row * 64 + c4 * 4];
        *(float4*)&Ko[row * 64 + c4 * 4] = kv;
        *(float4*)&Vo[row * 64 + c4 * 4] = vv;
        *(float4*)&Kl[row][c4 * 4] = kv;
        *(float4*)&Vl[row][c4 * 4] = vv;
    }
    __syncthreads();
    unsigned short* Kpb = Kp + (bh * 16 + kt) * 4096;
    unsigned short* Vpb = Vp + (bh * 16 + kt) * 4096;
    #pragma unroll
    for (int s = 0; s < 2; ++s) {
        int slot = t + s * 256;                 // 0..511
        int c = slot >> 6, l = slot & 63;
        int nn = c >> 1, hf = c & 1;
        {   // K chunk: K[key=nn*16+(l&15)][d=hf*32+(l>>4)*8 + j]
            int row = nn * 16 + (l & 15), col = hf * 32 + (l >> 4) * 8;
            unsigned short tmp[8];
            #pragma unroll
            for (int j = 0; j < 8; ++j) tmp[j] = f2bf(Kl[row][col + j]);
            *(uint4*)&Kpb[c * 512 + l * 8] = *(uint4*)tmp;
        }
        {   // V chunk: V[key=hf*32+(l>>4)*8+j][d=nn*16+(l&15)]
            int row0 = hf * 32 + (l >> 4) * 8, col = nn * 16 + (l & 15);
            unsigned short tmp[8];
            #pragma unroll
            for (int j = 0; j < 8; ++j) tmp[j] = f2bf(Vl[row0 + j][col]);
            *(uint4*)&Vpb[c * 512 + l * 8] = *(uint4*)tmp;
        }
    }
    __syncthreads();   // protect Kl/Vl reuse by the second pb unit
}

// ---------------------------------------------------------------------------
// MFMA GEMM, 2-phase double-buffered K-loop.
// CONV=true  (MODES 1/2/4): A/W read as fp32 and converted inline —
//   register-staged: loads for step t+1 issued BEFORE the MFMAs of step t,
//   cvt+ds_write after (latency hidden). LDS layout identical to gld16 path
//   (linear lane*16B writes, conflict-free). Kills the prep kernel.
// CONV=false (MODE 3): bf16 inputs via gld16 (barrier drains vmcnt).
// MODE 1: C bf16 *0.125*log2e scatter (B,H,S,DK)               [Q]
// MODE 2: C fp32 scatter (B,H,KL,DK) rows 512+, pack Kp tiles  [K]
// MODE 4: same as 2 but pack Vp tiles (d-major transpose)      [V]
// MODE 3: C fp32 row-major                                     [out]
// ---------------------------------------------------------------------------
template<int MODE, int BM, bool CONV>
__device__ __forceinline__
void mfma_gemm_body(const unsigned short* __restrict__ A,
                    const unsigned short* __restrict__ Wb,
                    const float* __restrict__ A32, const float* __restrict__ W32,
                    const float* __restrict__ bias,
                    float* __restrict__ C32, unsigned short* __restrict__ C16,
                    unsigned short* __restrict__ Pk,
                    unsigned char* __restrict__ smem) {
    constexpr int MM = BM / 32;                 // m-tiles per wave
    constexpr int ABUF = BM * 64;               // bytes per A-buffer
    const int t = threadIdx.x, l = t & 63, w = t >> 6;
    const int m16 = l & 15, quad = l >> 4;
    const int wm = w >> 1, wn = w & 1;
    const int bn = blockIdx.x, bm = blockIdx.y;
    const int lr = l >> 2, lc = (l & 3) * 8;    // 4 lanes per 64B row-piece

    f32x4 acc[MM][2] = {};
    const unsigned short* Ag = nullptr;
    const unsigned short* Wg = nullptr;
    const float* Ag32 = nullptr;
    const float* Wg32 = nullptr;
    if constexpr (CONV) {
        Ag32 = A32 + (bm * BM) * 512;
        Wg32 = W32 + (bn * 64) * 512;
    } else {
        Ag = A + (bm * BM) * 512;
        Wg = Wb + (bn * 64) * 512;
    }

    // --- gld16 staging (CONV=false) ---
    auto stage = [&](int buf, int k0) {
        unsigned short* Asb = (unsigned short*)(smem + buf * ABUF);
        unsigned short* Bsb = (unsigned short*)(smem + 2 * ABUF + buf * 4096);
        #pragma unroll
        for (int q = 0; q < BM / 64; ++q) {
            int chunk = w * (BM / 64) + q;
            gld16(Ag + (chunk * 16 + lr) * 512 + k0 + lc, &Asb[chunk * 512 + l * 8]);
        }
        gld16(Wg + (w * 16 + lr) * 512 + k0 + lc, &Bsb[w * 512 + l * 8]);
    };

    // --- fp32 reg staging (CONV=true, BM==128) ---
    // A: 512 slots (row=s>>2, c8=(s&3)*8), 2/thread; B: 256 slots, 1/thread.
    float4 ra[6];
    auto load_regs = [&](int k0) {
        if constexpr (CONV) {
            #pragma unroll
            for (int i = 0; i < 2; ++i) {
                int s = t + i * 256;
                int row = s >> 2, c8 = (s & 3) * 8;
                ra[i * 2 + 0] = *(const float4*)&Ag32[row * 512 + k0 + c8];
                ra[i * 2 + 1] = *(const float4*)&Ag32[row * 512 + k0 + c8 + 4];
            }
            int row = t >> 2, c8 = (t & 3) * 8;
            ra[4] = *(const float4*)&Wg32[row * 512 + k0 + c8];
            ra[5] = *(const float4*)&Wg32[row * 512 + k0 + c8 + 4];
        }
    };
    auto write_lds = [&](int buf) {
        if constexpr (CONV) {
            unsigned short* Asb = (unsigned short*)(smem + buf * ABUF);
            unsigned short* Bsb = (unsigned short*)(smem + 2 * ABUF + buf * 4096);
            #pragma unroll
            for (int i = 0; i < 2; ++i) {
                int s = t + i * 256;
                unsigned short tmp[8] = {
                    f2bf(ra[i * 2].x), f2bf(ra[i * 2].y), f2bf(ra[i * 2].z), f2bf(ra[i * 2].w),
                    f2bf(ra[i * 2 + 1].x), f2bf(ra[i * 2 + 1].y), f2bf(ra[i * 2 + 1].z), f2bf(ra[i * 2 + 1].w)};
                *(uint4*)&Asb[s * 8] = *(uint4*)tmp;   // s*8 shorts == row*32+c8 (linear)
            }
            unsigned short tmp[8] = {
                f2bf(ra[4].x), f2bf(ra[4].y), f2bf(ra[4].z), f2bf(ra[4].w),
                f2bf(ra[5].x), f2bf(ra[5].y), f2bf(ra[5].z), f2bf(ra[5].w)};
            *(uint4*)&Bsb[t * 8] = *(uint4*)tmp;
        }
    };

    if constexpr (CONV) { load_regs(0); write_lds(0); }
    else                { stage(0, 0); }
    __syncthreads();                            // buf0 ready (lgkm or vmcnt drain)
    int buf = 0;
    for (int it = 0; it < 16; ++it) {
        if (it < 15) {
            if constexpr (CONV) load_regs((it + 1) * 32);   // issue early
            else                stage(buf ^ 1, (it + 1) * 32);
        }

        const unsigned short* Asb = (const unsigned short*)(smem + buf * ABUF);
        const unsigned short* Bsb = (const unsigned short*)(smem + 2 * ABUF + buf * 4096);
        bf16x8 af[MM], bfr[2];
        #pragma unroll
        for (int mm = 0; mm < MM; ++mm)
            af[mm] = *(const bf16x8*)&Asb[(wm * (BM / 2) + mm * 16 + m16) * 32 + quad * 8];
        #pragma unroll
        for (int nn = 0; nn < 2; ++nn)
            bfr[nn] = *(const bf16x8*)&Bsb[(wn * 32 + nn * 16 + m16) * 32 + quad * 8];
        #pragma unroll
        for (int mm = 0; mm < MM; ++mm)
            #pragma unroll
            for (int nn = 0; nn < 2; ++nn)
                acc[mm][nn] = __builtin_amdgcn_mfma_f32_16x16x32_bf16(
                    af[mm], bfr[nn], acc[mm][nn], 0, 0, 0);

        if constexpr (CONV) { if (it < 15) write_lds(buf ^ 1); }  // waits vmcnt on ra
        __syncthreads();                        // next buf ready
        buf ^= 1;
    }

    // ---- epilogue: C/D row = quad*4+r, col = m16 [m89/m91] ----
    if constexpr (MODE == 2 || MODE == 4) {
        unsigned short* Ts = (unsigned short*)smem;   // 9216 bf16, aliases bufs
        #pragma unroll
        for (int mm = 0; mm < MM; ++mm)
            #pragma unroll
            for (int nn = 0; nn < 2; ++nn) {
                int n = bn * 64 + wn * 32 + nn * 16 + m16;
                float bv_ = bias[n];
                int d = n & 63;
                #pragma unroll
                for (int r = 0; r < 4; ++r) {
                    int ml = wm * (BM / 2) + mm * 16 + quad * 4 + r;
                    int m = bm * BM + ml;
                    float val = acc[mm][nn][r] + bv_;
                    int b = m >> 9, s = m & 511, h = n >> 6;
                    C32[((b * H_ + h) * KL_ + 512 + s) * DK_ + d] = val;
                    if (MODE == 2) Ts[ml * 72 + d]  = f2bf(val);   // key-major
                    else           Ts[d * 136 + ml] = f2bf(val);   // d-major
                }
            }
        __syncthreads();
        // two complete packed tiles per block (BM=128 rows = 2 key-tiles)
        const int bh = (bm >> 2) * H_ + bn;
        const int kt0 = 8 + (bm & 3) * 2;
        #pragma unroll
        for (int T = 0; T < 2; ++T)
            #pragma unroll
            for (int cp = 0; cp < 2; ++cp) {
                int c = w * 2 + cp, nn = c >> 1, hf = c & 1;
                uint4 frag;
                if (MODE == 2)
                    frag = *(const uint4*)&Ts[(T * 64 + nn * 16 + (l & 15)) * 72
                                              + hf * 32 + (l >> 4) * 8];
                else
                    frag = *(const uint4*)&Ts[(nn * 16 + (l & 15)) * 136
                                              + T * 64 + hf * 32 + (l >> 4) * 8];
                *(uint4*)&Pk[((bh * 16 + kt0 + T) * 4096) + c * 512 + l * 8] = frag;
            }
    } else {
        #pragma unroll
        for (int mm = 0; mm < MM; ++mm)
            #pragma unroll
            for (int nn = 0; nn < 2; ++nn) {
                int n = bn * 64 + wn * 32 + nn * 16 + m16;
                float bv_ = bias[n];
                #pragma unroll
                for (int r = 0; r < 4; ++r) {
                    int m = bm * BM + wm * (BM / 2) + mm * 16 + quad * 4 + r;
                    float val = acc[mm][nn][r] + bv_;
                    if (MODE == 3) {
                        C32[m * 512 + n] = val;
                    } else {                    // MODE 1: Q bf16 scatter, scaled
                        int b = m >> 9, s = m & 511;
                        int h = n >> 6, d = n & 63;
                        // 0.125 * log2(e): attn uses exp2 directly
                        C16[((b * H_ + h) * S_ + s) * DK_ + d] =
                            f2bf(val * 0.18033688011112042f);
                    }
                }
            }
    }
}

__global__ __launch_bounds__(256, 3)
void qkv_mfma_kernel(const float* __restrict__ x,
                     const float* __restrict__ Wq, const float* __restrict__ bq,
                     const float* __restrict__ Wk, const float* __restrict__ bk,
                     const float* __restrict__ Wv, const float* __restrict__ bv,
                     const float* __restrict__ Wo, unsigned short* __restrict__ Wob,
                     unsigned short* __restrict__ Qb, float* __restrict__ kout,
                     float* __restrict__ vout,
                     unsigned short* __restrict__ Kp, unsigned short* __restrict__ Vp,
                     const float* __restrict__ pk, const float* __restrict__ pv,
                     float* __restrict__ off_out) {
    // unioned LDS frame: GEMM dbuf path 24576 B, copy path 34816 B
    __shared__ __attribute__((aligned(16))) unsigned char smem[34816];
    if (blockIdx.z == 0) {                      // BW copy first in dispatch order
        int pb0 = blockIdx.y * 8 + blockIdx.x;  // 0..255
        if (pb0 == 0 && threadIdx.x == 0) off_out[0] = 1024.0f;
        {   // Wo -> bf16 (out-GEMM input; consumed 2 launches later)
            int base = pb0 * 1024 + threadIdx.x * 4;
            float4 wv = *(const float4*)&Wo[base];
            unsigned short tmp[4] = {f2bf(wv.x), f2bf(wv.y), f2bf(wv.z), f2bf(wv.w)};
            *(uint2*)&Wob[base] = *(uint2*)tmp;
        }
        prev_copy_body(pk, pv, kout, vout, Kp, Vp, smem, pb0);
        prev_copy_body(pk, pv, kout, vout, Kp, Vp, smem, pb0 + 256);
    }
    else if (blockIdx.z == 1)
        mfma_gemm_body<1, 128, true>(nullptr, nullptr, x, Wq, bq, nullptr, Qb, nullptr, smem);
    else if (blockIdx.z == 2)
        mfma_gemm_body<2, 128, true>(nullptr, nullptr, x, Wk, bk, kout, nullptr, Kp, smem);
    else
        mfma_gemm_body<4, 128, true>(nullptr, nullptr, x, Wv, bv, vout, nullptr, Vp, smem);
}

__global__ __launch_bounds__(256, 4)
void out_mfma_kernel(const unsigned short* __restrict__ Ob, const unsigned short* __restrict__ Wob,
                     const float* __restrict__ bo, float* __restrict__ C) {
    __shared__ __attribute__((aligned(16))) unsigned char smem[16384];
    mfma_gemm_body<3, 64, false>(Ob, Wob, nullptr, nullptr, bo, C, nullptr, nullptr, smem);
}

// ---------------------------------------------------------------------------
// Packed-fragment flash attention, no-max softmax on the exp2 path (scale
// folded into Q), split-K across 2 waves (UNsynchronized in the loop ->
// T5 setprio regime), ONE barrier for the combine. O -> row-major (B,S,D).
// ---------------------------------------------------------------------------
__global__ __launch_bounds__(128)
void attn_kernel(const unsigned short* __restrict__ Qb,
                 const unsigned short* __restrict__ Kp,
                 const unsigned short* __restrict__ Vp,
                 unsigned short* __restrict__ Ob) {
    const int bh = blockIdx.x, qg = blockIdx.y;
    const int t = threadIdx.x, l = t & 63, w = t >> 6;
    const int m16 = l & 15, quad = l >> 4;
    const int q0 = qg * 32;

    __shared__ __attribute__((aligned(16))) unsigned short Ps[2][32][72];
    __shared__ float comb[64][40];

    bf16x8 qf[2][2];
    #pragma unroll
    for (int qh = 0; qh < 2; ++qh)
        #pragma unroll
        for (int p = 0; p < 2; ++p)
            qf[qh][p] = *(const bf16x8*)(Qb + (bh * S_ + q0 + qh * 16 + m16) * DK_
                                            + p * 32 + quad * 8);

    f32x4 acc[2][4] = {};
    float psum[2][4] = {};

    const int ktmax = (543 + q0) >> 6;
    const unsigned short* Kpb = Kp + (bh * 16) * 4096;
    const unsigned short* Vpb = Vp + (bh * 16) * 4096;

    for (int kt = w; kt <= ktmax; kt += 2) {
        const unsigned short* kb = Kpb + kt * 4096;
        const unsigned short* vb = Vpb + kt * 4096;
        bf16x8 kf[4][2];
        #pragma unroll
        for (int nn = 0; nn < 4; ++nn)
            #pragma unroll
            for (int hf = 0; hf < 2; ++hf)
                kf[nn][hf] = *(const bf16x8*)(kb + ((nn * 2 + hf) * 64 + l) * 8);

        f32x4 sc[2][4];
        __builtin_amdgcn_s_setprio(1);
        #pragma unroll
        for (int qh = 0; qh < 2; ++qh)
            #pragma unroll
            for (int nn = 0; nn < 4; ++nn) {
                sc[qh][nn][0] = sc[qh][nn][1] = sc[qh][nn][2] = sc[qh][nn][3] = 0.f;
                sc[qh][nn] = __builtin_amdgcn_mfma_f32_16x16x32_bf16(qf[qh][0], kf[nn][0], sc[qh][nn], 0, 0, 0);
                sc[qh][nn] = __builtin_amdgcn_mfma_f32_16x16x32_bf16(qf[qh][1], kf[nn][1], sc[qh][nn], 0, 0, 0);
            }
        __builtin_amdgcn_s_setprio(0);

        // V loads issued here: VMEM latency hides under the exp/pack VALU phase
        bf16x8 vf[4][2];
        #pragma unroll
        for (int nn = 0; nn < 4; ++nn)
            #pragma unroll
            for (int hf = 0; hf < 2; ++hf)
                vf[nn][hf] = *(const bf16x8*)(vb + ((nn * 2 + hf) * 64 + l) * 8);

        if (kt == ktmax) {                      // causal mask, boundary tile only
            #pragma unroll
            for (int qh = 0; qh < 2; ++qh)
                #pragma unroll
                for (int nn = 0; nn < 4; ++nn) {
                    int key = kt * 64 + nn * 16 + m16;
                    #pragma unroll
                    for (int r = 0; r < 4; ++r)
                        if (key > 512 + q0 + qh * 16 + (quad << 2) + r)
                            sc[qh][nn][r] = -INFINITY;
                }
        }

        #pragma unroll
        for (int qh = 0; qh < 2; ++qh)
            #pragma unroll
            for (int nn = 0; nn < 4; ++nn)
                #pragma unroll
                for (int r = 0; r < 4; ++r) {
                    float p = exp2f(sc[qh][nn][r]);   // scale pre-folded into Q
                    psum[qh][r] += p;
                    Ps[w][qh * 16 + (quad << 2) + r][nn * 16 + m16] = f2bf(p);
                }

        bf16x8 pf[2][2];
        #pragma unroll
        for (int qh = 0; qh < 2; ++qh)
            #pragma unroll
            for (int hf = 0; hf < 2; ++hf)
                pf[qh][hf] = *(const bf16x8*)&Ps[w][qh * 16 + m16][hf * 32 + quad * 8];
        __builtin_amdgcn_s_setprio(1);
        #pragma unroll
        for (int qh = 0; qh < 2; ++qh)
            #pragma unroll
            for (int nn = 0; nn < 4; ++nn) {
                acc[qh][nn] = __builtin_amdgcn_mfma_f32_16x16x32_bf16(pf[qh][0], vf[nn][0], acc[qh][nn], 0, 0, 0);
                acc[qh][nn] = __builtin_amdgcn_mfma_f32_16x16x32_bf16(pf[qh][1], vf[nn][1], acc[qh][nn], 0, 0, 0);
            }
        __builtin_amdgcn_s_setprio(0);
    }

    if (w == 0) {
        #pragma unroll
        for (int qh = 0; qh < 2; ++qh)
            #pragma unroll
            for (int nn = 0; nn < 4; ++nn)
                #pragma unroll
                for (int r = 0; r < 4; ++r)
                    comb[l][(qh * 4 + nn) * 4 + r] = acc[qh][nn][r];
        #pragma unroll
        for (int qh = 0; qh < 2; ++qh)
            #pragma unroll
            for (int r = 0; r < 4; ++r)
                comb[l][32 + qh * 4 + r] = psum[qh][r];
    }
    __syncthreads();
    if (w == 1) {
        #pragma unroll
        for (int qh = 0; qh < 2; ++qh)
            #pragma unroll
            for (int nn = 0; nn < 4; ++nn)
                #pragma unroll
                for (int r = 0; r < 4; ++r)
                    acc[qh][nn][r] += comb[l][(qh * 4 + nn) * 4 + r];
        float inv[2][4];
        #pragma unroll
        for (int qh = 0; qh < 2; ++qh)
            #pragma unroll
            for (int r = 0; r < 4; ++r) {
                float ps = psum[qh][r] + comb[l][32 + qh * 4 + r];
                ps += __shfl_xor(ps, 1);
                ps += __shfl_xor(ps, 2);
                ps += __shfl_xor(ps, 4);
                ps += __shfl_xor(ps, 8);
                inv[qh][r] = 1.f / ps;
            }
        // O row-major (B,S,D): row b*512 + q, col h*64 + d
        unsigned short* Og = Ob + ((bh >> 3) * S_ + q0) * D_ + (bh & 7) * DK_;
        #pragma unroll
        for (int qh = 0; qh < 2; ++qh)
            #pragma unroll
            for (int r = 0; r < 4; ++r)
                #pragma unroll
                for (int nn = 0; nn < 4; ++nn)
                    Og[(qh * 16 + (quad << 2) + r) * D_ + nn * 16 + m16] =
                        f2bf(acc[qh][nn][r] * inv[qh][r]);
    }
}

// ---------------------------------------------------------------------------
extern "C" void kernel_launch(void* const* d_in, const int* in_sizes, int n_in,
                              void* d_out, int out_size, void* d_ws, size_t ws_size,
                              hipStream_t stream) {
    const float* x  = (const float*)d_in[0];
    const float* pk = (const float*)d_in[1];
    const float* pv = (const float*)d_in[2];
    const float* Wq = (const float*)d_in[3];
    const float* bq = (const float*)d_in[4];
    const float* Wk = (const float*)d_in[5];
    const float* bk = (const float*)d_in[6];
    const float* Wv = (const float*)d_in[7];
    const float* bv = (const float*)d_in[8];
    const float* Wo = (const float*)d_in[9];
    const float* bo = (const float*)d_in[10];

    float* out     = (float*)d_out;             // (8,512,512)
    float* kout    = out + 2097152;             // (8,8,1024,64)
    float* vout    = kout + 4194304;            // (8,8,1024,64)
    float* off_out = vout + 4194304;            // scalar 1024.0

    // workspace layout (bf16 elements):
    unsigned short* Ob  = (unsigned short*)d_ws;  // [0,4MB)   O bf16 (B,S,D) row-major
    unsigned short* Wob = Ob + 2097152;           // [4,4.5MB) Wo bf16 (made by qkv z=0)
    unsigned short* Qb  = Wob + 262144;           // [4.5,8.5MB) Q bf16 (B,H,S,DK), pre-scaled
    unsigned short* Kp  = Qb + 2097152;           // [8.5,16.5MB) packed K fragments
    unsigned short* Vp  = Kp + 4194304;           // [16.5,24.5MB) packed V fragments

    // 1) prev cache copy/pack + Wo convert (z=0, dispatched first)
    //    + QKV projections with inline fp32->bf16 staging (z=1..3)
    qkv_mfma_kernel<<<dim3(8, 32, 4), 256, 0, stream>>>(x, Wq, bq, Wk, bk, Wv, bv,
                                                        Wo, Wob, Qb, kout, vout,
                                                        Kp, Vp, pk, pv, off_out);
    // 2) attention; O -> row-major bf16
    attn_kernel<<<dim3(64, 16), 128, 0, stream>>>(Qb, Kp, Vp, Ob);
    // 3) output projection (both operands bf16)
    out_mfma_kernel<<<dim3(8, 64), 256, 0, stream>>>(Ob, Wob, bo, out);
}

// Round 4
// 154.543 us; speedup vs baseline: 1.0155x; 1.0155x over previous
//
#include <hip/hip_runtime.h>
#include <hip/hip_bf16.h>
#include <math.h>

#define B_  8
#define S_  512
#define D_  512
#define H_  8
#define DK_ 64
#define KL_ 1024

typedef __attribute__((ext_vector_type(8))) short bf16x8;
typedef __attribute__((ext_vector_type(4))) float f32x4;

// native RNE cast: backend pairs adjacent converts into v_cvt_pk_bf16_f32
__device__ __forceinline__ unsigned short f2bf(float f) {
    __hip_bfloat16 h = __float2bfloat16(f);
    unsigned short u;
    __builtin_memcpy(&u, &h, 2);
    return u;
}
// async global->LDS, 16 B per lane; LDS dest = wave-uniform base + lane*16
__device__ __forceinline__ void gld16(const void* g, void* l) {
    __builtin_amdgcn_global_load_lds(
        (const __attribute__((address_space(1))) unsigned int*)g,
        (__attribute__((address_space(3))) unsigned int*)l, 16, 0, 0);
}

// ---------------------------------------------------------------------------
// prep (grid 1408): pure fp32 -> bf16 converts (x + Wq/Wk/Wv).
// Wo is converted by qkv's copy slice (consumed two launches later).
// ---------------------------------------------------------------------------
__global__ __launch_bounds__(256)
void prep_kernel(const float* __restrict__ x,
                 const float* __restrict__ Wq, const float* __restrict__ Wk,
                 const float* __restrict__ Wv,
                 unsigned short* __restrict__ xb,
                 unsigned short* __restrict__ Wqb, unsigned short* __restrict__ Wkb,
                 unsigned short* __restrict__ Wvb,
                 float* __restrict__ off_out) {
    const int blk = blockIdx.x, t = threadIdx.x;
    if (blk == 0 && t == 0) off_out[0] = 1024.0f;

    const float* src; unsigned short* dst; int off;
    if (blk < 1024) {
        src = x; dst = xb; off = blk * 256 + t;                 // [0, 262144)
    } else {
        int widx = blk - 1024;                                  // 0..383
        int grp = widx >> 7, wb = widx & 127;
        const float* ws_[3]        = {Wq, Wk, Wv};
        unsigned short* wd_[3]     = {Wqb, Wkb, Wvb};
        src = ws_[grp]; dst = wd_[grp]; off = wb * 256 + t;     // [0, 32768)
    }
    float4 v0 = ((const float4*)src)[off * 2];
    float4 v1 = ((const float4*)src)[off * 2 + 1];
    unsigned short tmp[8] = {f2bf(v0.x), f2bf(v0.y), f2bf(v0.z), f2bf(v0.w),
                             f2bf(v1.x), f2bf(v1.y), f2bf(v1.z), f2bf(v1.w)};
    *(uint4*)&dst[off * 8] = *(uint4*)tmp;
}

// ---------------------------------------------------------------------------
// prev cache copy + pack (blockIdx.z==0 of qkv, dispatched first: pure-BW
// traffic overlaps the compute-bound GEMM z-slices).
// ---------------------------------------------------------------------------
__device__ __forceinline__
void prev_copy_body(const float* __restrict__ pk, const float* __restrict__ pv,
                    float* __restrict__ kout, float* __restrict__ vout,
                    unsigned short* __restrict__ Kp, unsigned short* __restrict__ Vp,
                    unsigned char* __restrict__ smem, int pb) {
    float (*Kl)[68] = (float (*)[68])smem;             // 64*68*4 = 17408 B
    float (*Vl)[68] = (float (*)[68])(smem + 17408);   // 17408 B
    const int t = threadIdx.x;
    const int kt = pb & 7, bh = pb >> 3;
    const float* Kg = pk + (bh * KL_ + 512 + kt * 64) * DK_;
    const float* Vg = pv + (bh * KL_ + 512 + kt * 64) * DK_;
    float* Ko = kout + (bh * KL_ + kt * 64) * DK_;
    float* Vo = vout + (bh * KL_ + kt * 64) * DK_;
    #pragma unroll
    for (int it = 0; it < 4; ++it) {
        int idx = t + it * 256;                 // 1024 float4 slots
        int row = idx >> 4, c4 = idx & 15;
        float4 kv = *(const float4*)&Kg[row * 64 + c4 * 4];
        float4 vv = *(const float4*)&Vg[row * 64 + c4 * 4];
        *(float4*)&Ko[row * 64 + c4 * 4] = kv;
        *(float4*)&Vo[row * 64 + c4 * 4] = vv;
        *(float4*)&Kl[row][c4 * 4] = kv;
        *(float4*)&Vl[row][c4 * 4] = vv;
    }
    __syncthreads();
    unsigned short* Kpb = Kp + (bh * 16 + kt) * 4096;
    unsigned short* Vpb = Vp + (bh * 16 + kt) * 4096;
    #pragma unroll
    for (int s = 0; s < 2; ++s) {
        int slot = t + s * 256;                 // 0..511
        int c = slot >> 6, l = slot & 63;
        int nn = c >> 1, hf = c & 1;
        {   // K chunk: K[key=nn*16+(l&15)][d=hf*32+(l>>4)*8 + j]
            int row = nn * 16 + (l & 15), col = hf * 32 + (l >> 4) * 8;
            unsigned short tmp[8];
            #pragma unroll
            for (int j = 0; j < 8; ++j) tmp[j] = f2bf(Kl[row][col + j]);
            *(uint4*)&Kpb[c * 512 + l * 8] = *(uint4*)tmp;
        }
        {   // V chunk: V[key=hf*32+(l>>4)*8+j][d=nn*16+(l&15)]
            int row0 = hf * 32 + (l >> 4) * 8, col = nn * 16 + (l & 15);
            unsigned short tmp[8];
            #pragma unroll
            for (int j = 0; j < 8; ++j) tmp[j] = f2bf(Vl[row0 + j][col]);
            *(uint4*)&Vpb[c * 512 + l * 8] = *(uint4*)tmp;
        }
    }
    __syncthreads();   // protect Kl/Vl reuse by the second pb unit
}

// ---------------------------------------------------------------------------
// MFMA GEMM, 2-phase double-buffered K-loop: STAGE(next) issued BEFORE
// compute(cur); ONE barrier (vmcnt(0) drain) per K-step. bf16 inputs via
// gld16 (the measured-best staging path).
// MODE 1: C bf16 *0.125*log2e scatter (B,H,S,DK)               [Q]
// MODE 2: C fp32 scatter (B,H,KL,DK) rows 512+, pack Kp tiles  [K]
// MODE 4: same as 2 but pack Vp tiles (d-major transpose)      [V]
// MODE 3: C fp32 row-major                                     [out]
// ---------------------------------------------------------------------------
template<int MODE, int BM>
__device__ __forceinline__
void mfma_gemm_body(const unsigned short* __restrict__ A,
                    const unsigned short* __restrict__ Wb,
                    const float* __restrict__ bias,
                    float* __restrict__ C32, unsigned short* __restrict__ C16,
                    unsigned short* __restrict__ Pk,
                    unsigned char* __restrict__ smem) {
    constexpr int MM = BM / 32;                 // m-tiles per wave
    constexpr int ABUF = BM * 64;               // bytes per A-buffer
    const int t = threadIdx.x, l = t & 63, w = t >> 6;
    const int m16 = l & 15, quad = l >> 4;
    const int wm = w >> 1, wn = w & 1;
    const int bn = blockIdx.x, bm = blockIdx.y;
    const int lr = l >> 2, lc = (l & 3) * 8;    // 4 lanes per 64B row-piece

    f32x4 acc[MM][2] = {};
    const unsigned short* Ag = A + (bm * BM) * 512;
    const unsigned short* Wg = Wb + (bn * 64) * 512;

    auto stage = [&](int buf, int k0) {
        unsigned short* Asb = (unsigned short*)(smem + buf * ABUF);
        unsigned short* Bsb = (unsigned short*)(smem + 2 * ABUF + buf * 4096);
        #pragma unroll
        for (int q = 0; q < BM / 64; ++q) {
            int chunk = w * (BM / 64) + q;
            gld16(Ag + (chunk * 16 + lr) * 512 + k0 + lc, &Asb[chunk * 512 + l * 8]);
        }
        gld16(Wg + (w * 16 + lr) * 512 + k0 + lc, &Bsb[w * 512 + l * 8]);
    };

    stage(0, 0);
    __syncthreads();                            // drains vmcnt(0): buf0 ready
    int buf = 0;
    for (int it = 0; it < 16; ++it) {
        if (it < 15) stage(buf ^ 1, (it + 1) * 32);   // in flight during MFMA

        const unsigned short* Asb = (const unsigned short*)(smem + buf * ABUF);
        const unsigned short* Bsb = (const unsigned short*)(smem + 2 * ABUF + buf * 4096);
        bf16x8 af[MM], bfr[2];
        #pragma unroll
        for (int mm = 0; mm < MM; ++mm)
            af[mm] = *(const bf16x8*)&Asb[(wm * (BM / 2) + mm * 16 + m16) * 32 + quad * 8];
        #pragma unroll
        for (int nn = 0; nn < 2; ++nn)
            bfr[nn] = *(const bf16x8*)&Bsb[(wn * 32 + nn * 16 + m16) * 32 + quad * 8];
        #pragma unroll
        for (int mm = 0; mm < MM; ++mm)
            #pragma unroll
            for (int nn = 0; nn < 2; ++nn)
                acc[mm][nn] = __builtin_amdgcn_mfma_f32_16x16x32_bf16(
                    af[mm], bfr[nn], acc[mm][nn], 0, 0, 0);

        __syncthreads();                        // vmcnt(0): next buf ready
        buf ^= 1;
    }

    // ---- epilogue: C/D row = quad*4+r, col = m16 [m89/m91] ----
    if constexpr (MODE == 2 || MODE == 4) {
        unsigned short* Ts = (unsigned short*)smem;   // 9216 bf16, aliases bufs
        #pragma unroll
        for (int mm = 0; mm < MM; ++mm)
            #pragma unroll
            for (int nn = 0; nn < 2; ++nn) {
                int n = bn * 64 + wn * 32 + nn * 16 + m16;
                float bv_ = bias[n];
                int d = n & 63;
                #pragma unroll
                for (int r = 0; r < 4; ++r) {
                    int ml = wm * (BM / 2) + mm * 16 + quad * 4 + r;
                    int m = bm * BM + ml;
                    float val = acc[mm][nn][r] + bv_;
                    int b = m >> 9, s = m & 511, h = n >> 6;
                    C32[((b * H_ + h) * KL_ + 512 + s) * DK_ + d] = val;
                    if (MODE == 2) Ts[ml * 72 + d]  = f2bf(val);   // key-major
                    else           Ts[d * 136 + ml] = f2bf(val);   // d-major
                }
            }
        __syncthreads();
        // two complete packed tiles per block (BM=128 rows = 2 key-tiles)
        const int bh = (bm >> 2) * H_ + bn;
        const int kt0 = 8 + (bm & 3) * 2;
        #pragma unroll
        for (int T = 0; T < 2; ++T)
            #pragma unroll
            for (int cp = 0; cp < 2; ++cp) {
                int c = w * 2 + cp, nn = c >> 1, hf = c & 1;
                uint4 frag;
                if (MODE == 2)
                    frag = *(const uint4*)&Ts[(T * 64 + nn * 16 + (l & 15)) * 72
                                              + hf * 32 + (l >> 4) * 8];
                else
                    frag = *(const uint4*)&Ts[(nn * 16 + (l & 15)) * 136
                                              + T * 64 + hf * 32 + (l >> 4) * 8];
                *(uint4*)&Pk[((bh * 16 + kt0 + T) * 4096) + c * 512 + l * 8] = frag;
            }
    } else {
        #pragma unroll
        for (int mm = 0; mm < MM; ++mm)
            #pragma unroll
            for (int nn = 0; nn < 2; ++nn) {
                int n = bn * 64 + wn * 32 + nn * 16 + m16;
                float bv_ = bias[n];
                #pragma unroll
                for (int r = 0; r < 4; ++r) {
                    int m = bm * BM + wm * (BM / 2) + mm * 16 + quad * 4 + r;
                    float val = acc[mm][nn][r] + bv_;
                    if (MODE == 3) {
                        C32[m * 512 + n] = val;
                    } else {                    // MODE 1: Q bf16 scatter, scaled
                        int b = m >> 9, s = m & 511;
                        int h = n >> 6, d = n & 63;
                        // 0.125 * log2(e): attn uses exp2 directly
                        C16[((b * H_ + h) * S_ + s) * DK_ + d] =
                            f2bf(val * 0.18033688011112042f);
                    }
                }
            }
    }
}

__global__ __launch_bounds__(256, 4)
void qkv_mfma_kernel(const unsigned short* __restrict__ xb,
                     const unsigned short* __restrict__ Wqb, const float* __restrict__ bq,
                     const unsigned short* __restrict__ Wkb, const float* __restrict__ bk,
                     const unsigned short* __restrict__ Wvb, const float* __restrict__ bv,
                     const float* __restrict__ Wo, unsigned short* __restrict__ Wob,
                     unsigned short* __restrict__ Qb, float* __restrict__ kout,
                     float* __restrict__ vout,
                     unsigned short* __restrict__ Kp, unsigned short* __restrict__ Vp,
                     const float* __restrict__ pk, const float* __restrict__ pv) {
    // unioned LDS frame: GEMM dbuf path 24576 B, copy path 34816 B
    __shared__ __attribute__((aligned(16))) unsigned char smem[34816];
    if (blockIdx.z == 0) {                      // BW copy first in dispatch order
        int pb0 = blockIdx.y * 8 + blockIdx.x;  // 0..255
        {   // Wo -> bf16 (out-GEMM input; consumed two launches later)
            int base = pb0 * 1024 + threadIdx.x * 4;
            float4 wv = *(const float4*)&Wo[base];
            unsigned short tmp[4] = {f2bf(wv.x), f2bf(wv.y), f2bf(wv.z), f2bf(wv.w)};
            *(uint2*)&Wob[base] = *(uint2*)tmp;
        }
        prev_copy_body(pk, pv, kout, vout, Kp, Vp, smem, pb0);
        prev_copy_body(pk, pv, kout, vout, Kp, Vp, smem, pb0 + 256);
    }
    else if (blockIdx.z == 1) mfma_gemm_body<1, 128>(xb, Wqb, bq, nullptr, Qb, nullptr, smem);
    else if (blockIdx.z == 2) mfma_gemm_body<2, 128>(xb, Wkb, bk, kout, nullptr, Kp, smem);
    else                      mfma_gemm_body<4, 128>(xb, Wvb, bv, vout, nullptr, Vp, smem);
}

__global__ __launch_bounds__(256, 4)
void out_mfma_kernel(const unsigned short* __restrict__ Ob, const unsigned short* __restrict__ Wob,
                     const float* __restrict__ bo, float* __restrict__ C) {
    __shared__ __attribute__((aligned(16))) unsigned char smem[16384];
    mfma_gemm_body<3, 64>(Ob, Wob, bo, C, nullptr, nullptr, smem);
}

// ---------------------------------------------------------------------------
// Packed-fragment flash attention, no-max softmax on the exp2 path (scale
// folded into Q), split-K across 2 waves (UNsynchronized in the loop ->
// T5 setprio regime), ONE barrier for the combine. O -> row-major (B,S,D).
// ---------------------------------------------------------------------------
__global__ __launch_bounds__(128)
void attn_kernel(const unsigned short* __restrict__ Qb,
                 const unsigned short* __restrict__ Kp,
                 const unsigned short* __restrict__ Vp,
                 unsigned short* __restrict__ Ob) {
    const int bh = blockIdx.x, qg = blockIdx.y;
    const int t = threadIdx.x, l = t & 63, w = t >> 6;
    const int m16 = l & 15, quad = l >> 4;
    const int q0 = qg * 32;

    __shared__ __attribute__((aligned(16))) unsigned short Ps[2][32][72];
    __shared__ float comb[64][40];

    bf16x8 qf[2][2];
    #pragma unroll
    for (int qh = 0; qh < 2; ++qh)
        #pragma unroll
        for (int p = 0; p < 2; ++p)
            qf[qh][p] = *(const bf16x8*)(Qb + (bh * S_ + q0 + qh * 16 + m16) * DK_
                                            + p * 32 + quad * 8);

    f32x4 acc[2][4] = {};
    float psum[2][4] = {};

    const int ktmax = (543 + q0) >> 6;
    const unsigned short* Kpb = Kp + (bh * 16) * 4096;
    const unsigned short* Vpb = Vp + (bh * 16) * 4096;

    for (int kt = w; kt <= ktmax; kt += 2) {
        const unsigned short* kb = Kpb + kt * 4096;
        const unsigned short* vb = Vpb + kt * 4096;
        bf16x8 kf[4][2];
        #pragma unroll
        for (int nn = 0; nn < 4; ++nn)
            #pragma unroll
            for (int hf = 0; hf < 2; ++hf)
                kf[nn][hf] = *(const bf16x8*)(kb + ((nn * 2 + hf) * 64 + l) * 8);

        f32x4 sc[2][4];
        __builtin_amdgcn_s_setprio(1);
        #pragma unroll
        for (int qh = 0; qh < 2; ++qh)
            #pragma unroll
            for (int nn = 0; nn < 4; ++nn) {
                sc[qh][nn][0] = sc[qh][nn][1] = sc[qh][nn][2] = sc[qh][nn][3] = 0.f;
                sc[qh][nn] = __builtin_amdgcn_mfma_f32_16x16x32_bf16(qf[qh][0], kf[nn][0], sc[qh][nn], 0, 0, 0);
                sc[qh][nn] = __builtin_amdgcn_mfma_f32_16x16x32_bf16(qf[qh][1], kf[nn][1], sc[qh][nn], 0, 0, 0);
            }
        __builtin_amdgcn_s_setprio(0);

        // V loads issued here: VMEM latency hides under the exp/pack VALU phase
        bf16x8 vf[4][2];
        #pragma unroll
        for (int nn = 0; nn < 4; ++nn)
            #pragma unroll
            for (int hf = 0; hf < 2; ++hf)
                vf[nn][hf] = *(const bf16x8*)(vb + ((nn * 2 + hf) * 64 + l) * 8);

        if (kt == ktmax) {                      // causal mask, boundary tile only
            #pragma unroll
            for (int qh = 0; qh < 2; ++qh)
                #pragma unroll
                for (int nn = 0; nn < 4; ++nn) {
                    int key = kt * 64 + nn * 16 + m16;
                    #pragma unroll
                    for (int r = 0; r < 4; ++r)
                        if (key > 512 + q0 + qh * 16 + (quad << 2) + r)
                            sc[qh][nn][r] = -INFINITY;
                }
        }

        #pragma unroll
        for (int qh = 0; qh < 2; ++qh)
            #pragma unroll
            for (int nn = 0; nn < 4; ++nn)
                #pragma unroll
                for (int r = 0; r < 4; ++r) {
                    float p = exp2f(sc[qh][nn][r]);   // scale pre-folded into Q
                    psum[qh][r] += p;
                    Ps[w][qh * 16 + (quad << 2) + r][nn * 16 + m16] = f2bf(p);
                }

        bf16x8 pf[2][2];
        #pragma unroll
        for (int qh = 0; qh < 2; ++qh)
            #pragma unroll
            for (int hf = 0; hf < 2; ++hf)
                pf[qh][hf] = *(const bf16x8*)&Ps[w][qh * 16 + m16][hf * 32 + quad * 8];
        __builtin_amdgcn_s_setprio(1);
        #pragma unroll
        for (int qh = 0; qh < 2; ++qh)
            #pragma unroll
            for (int nn = 0; nn < 4; ++nn) {
                acc[qh][nn] = __builtin_amdgcn_mfma_f32_16x16x32_bf16(pf[qh][0], vf[nn][0], acc[qh][nn], 0, 0, 0);
                acc[qh][nn] = __builtin_amdgcn_mfma_f32_16x16x32_bf16(pf[qh][1], vf[nn][1], acc[qh][nn], 0, 0, 0);
            }
        __builtin_amdgcn_s_setprio(0);
    }

    if (w == 0) {
        #pragma unroll
        for (int qh = 0; qh < 2; ++qh)
            #pragma unroll
            for (int nn = 0; nn < 4; ++nn)
                #pragma unroll
                for (int r = 0; r < 4; ++r)
                    comb[l][(qh * 4 + nn) * 4 + r] = acc[qh][nn][r];
        #pragma unroll
        for (int qh = 0; qh < 2; ++qh)
            #pragma unroll
            for (int r = 0; r < 4; ++r)
                comb[l][32 + qh * 4 + r] = psum[qh][r];
    }
    __syncthreads();
    if (w == 1) {
        #pragma unroll
        for (int qh = 0; qh < 2; ++qh)
            #pragma unroll
            for (int nn = 0; nn < 4; ++nn)
                #pragma unroll
                for (int r = 0; r < 4; ++r)
                    acc[qh][nn][r] += comb[l][(qh * 4 + nn) * 4 + r];
        float inv[2][4];
        #pragma unroll
        for (int qh = 0; qh < 2; ++qh)
            #pragma unroll
            for (int r = 0; r < 4; ++r) {
                float ps = psum[qh][r] + comb[l][32 + qh * 4 + r];
                ps += __shfl_xor(ps, 1);
                ps += __shfl_xor(ps, 2);
                ps += __shfl_xor(ps, 4);
                ps += __shfl_xor(ps, 8);
                inv[qh][r] = 1.f / ps;
            }
        // O row-major (B,S,D): row b*512 + q, col h*64 + d
        unsigned short* Og = Ob + ((bh >> 3) * S_ + q0) * D_ + (bh & 7) * DK_;
        #pragma unroll
        for (int qh = 0; qh < 2; ++qh)
            #pragma unroll
            for (int r = 0; r < 4; ++r)
                #pragma unroll
                for (int nn = 0; nn < 4; ++nn)
                    Og[(qh * 16 + (quad << 2) + r) * D_ + nn * 16 + m16] =
                        f2bf(acc[qh][nn][r] * inv[qh][r]);
    }
}

// ---------------------------------------------------------------------------
extern "C" void kernel_launch(void* const* d_in, const int* in_sizes, int n_in,
                              void* d_out, int out_size, void* d_ws, size_t ws_size,
                              hipStream_t stream) {
    const float* x  = (const float*)d_in[0];
    const float* pk = (const float*)d_in[1];
    const float* pv = (const float*)d_in[2];
    const float* Wq = (const float*)d_in[3];
    const float* bq = (const float*)d_in[4];
    const float* Wk = (const float*)d_in[5];
    const float* bk = (const float*)d_in[6];
    const float* Wv = (const float*)d_in[7];
    const float* bv = (const float*)d_in[8];
    const float* Wo = (const float*)d_in[9];
    const float* bo = (const float*)d_in[10];

    float* out     = (float*)d_out;             // (8,512,512)
    float* kout    = out + 2097152;             // (8,8,1024,64)
    float* vout    = kout + 4194304;            // (8,8,1024,64)
    float* off_out = vout + 4194304;            // scalar 1024.0

    // workspace layout (bf16 elements), 26 MB total:
    unsigned short* xb  = (unsigned short*)d_ws;  // [0,4MB)  x bf16; Ob aliases after qkv
    unsigned short* Wqb = xb + 2097152;           // [4,4.5MB)
    unsigned short* Wkb = Wqb + 262144;           // [4.5,5MB)
    unsigned short* Wvb = Wkb + 262144;           // [5,5.5MB)
    unsigned short* Wob = Wvb + 262144;           // [5.5,6MB) (made by qkv z=0)
    unsigned short* Qb  = Wob + 262144;           // [6,10MB)  Q bf16 (B,H,S,DK), pre-scaled
    unsigned short* Kp  = Qb + 2097152;           // [10,18MB) packed K fragments
    unsigned short* Vp  = Kp + 4194304;           // [18,26MB) packed V fragments
    unsigned short* Ob  = xb;                     // O bf16 (B,S,D) row-major (xb dead)

    // 1) dtype converts (x, Wq/Wk/Wv) + offset
    prep_kernel<<<1408, 256, 0, stream>>>(x, Wq, Wk, Wv,
                                          xb, Wqb, Wkb, Wvb, off_out);
    // 2) prev cache copy/pack + Wo convert (z=0, dispatched first)
    //    + QKV projections (z=1..3)
    qkv_mfma_kernel<<<dim3(8, 32, 4), 256, 0, stream>>>(xb, Wqb, bq, Wkb, bk, Wvb, bv,
                                                        Wo, Wob, Qb, kout, vout,
                                                        Kp, Vp, pk, pv);
    // 3) attention; O -> row-major bf16
    attn_kernel<<<dim3(64, 16), 128, 0, stream>>>(Qb, Kp, Vp, Ob);
    // 4) output projection (both operands bf16)
    out_mfma_kernel<<<dim3(8, 64), 256, 0, stream>>>(Ob, Wob, bo, out);
}